// Round 19
// baseline (263.291 us; speedup 1.0000x reference)
//
#include <hip/hip_runtime.h>

#define B_ 2
#define S_ 2048
#define D_ 1024
#define H_ 16
#define DH_ 64
#define DF_ 4096
#define M_ (B_*S_)   // 4096

typedef __bf16 bf16_t;
typedef __attribute__((ext_vector_type(4))) __bf16 bf16x4;
typedef __attribute__((ext_vector_type(8))) __bf16 bf16x8;
typedef __attribute__((ext_vector_type(4))) float f32x4;

__device__ inline f32x4 mfma16(bf16x8 a, bf16x8 b, f32x4 c){
  return __builtin_amdgcn_mfma_f32_16x16x32_bf16(a, b, c, 0, 0, 0);
}

__device__ inline void glds16(const void* g, void* l){
  __builtin_amdgcn_global_load_lds((const __attribute__((address_space(1))) void*)g,
                                   (__attribute__((address_space(3))) void*)l, 16, 0, 0);
}

// ---- batched transpose fp32 [z][K][N] -> bf16 [z][N][K] ----
__global__ __launch_bounds__(256) void transpose_f2b_k(const float* __restrict__ in,
                                                       bf16_t* __restrict__ out,
                                                       int K, int N){
  __shared__ float t[32][33];
  const size_t zoff = (size_t)blockIdx.z * K * N;
  in  += zoff; out += zoff;
  int kb = blockIdx.x * 32, nb = blockIdx.y * 32;
  for (int i = threadIdx.y; i < 32; i += 8)
    t[i][threadIdx.x] = in[(size_t)(kb + i) * N + nb + threadIdx.x];
  __syncthreads();
  for (int i = threadIdx.y; i < 32; i += 8)
    out[(size_t)(nb + i) * K + kb + threadIdx.x] = (bf16_t)t[threadIdx.x][i];
}

// ---- LayerNorm fp32 row -> bf16 ----
__global__ __launch_bounds__(256) void ln_k(const float* __restrict__ x,
                                            const float* __restrict__ g,
                                            const float* __restrict__ o,
                                            bf16_t* __restrict__ out){
  int row = blockIdx.x;
  const float* xr = x + (size_t)row * D_;
  f32x4 v = *((const f32x4*)xr + threadIdx.x);
  float s  = v[0] + v[1] + v[2] + v[3];
  float sq = v[0]*v[0] + v[1]*v[1] + v[2]*v[2] + v[3]*v[3];
  #pragma unroll
  for (int off = 1; off < 64; off <<= 1){
    s  += __shfl_xor(s, off);
    sq += __shfl_xor(sq, off);
  }
  __shared__ float ss[4], ssq[4];
  int wid = threadIdx.x >> 6;
  if ((threadIdx.x & 63) == 0){ ss[wid] = s; ssq[wid] = sq; }
  __syncthreads();
  s  = ss[0] + ss[1] + ss[2] + ss[3];
  sq = ssq[0] + ssq[1] + ssq[2] + ssq[3];
  float mean = s * (1.0f / D_);
  float var  = fmaxf(sq * (1.0f / D_) - mean * mean, 0.0f);
  float inv  = 1.0f / (sqrtf(var) + 1e-9f);
  int c = threadIdx.x * 4;
  bf16_t* orow = out + (size_t)row * D_;
  #pragma unroll
  for (int j = 0; j < 4; j++)
    orow[c + j] = (bf16_t)(g[c + j] * ((v[j] - mean) * inv) + o[c + j]);
}

// ---- 128xBN-tile GEMM, BK=32, double-buffered, counted vmcnt, 0-conflict ----
// R19: 64^2 tile was L2-BW-bound (0.031 B/FLOP * 34.4 GFLOP = 1.07GB @ 18.7
// TB/s == measured 57us). 128^2 halves traffic (0.0153), 128x64 = 0.023.
// This kernel = old gemm_k shape + R18 dbuf/counted-vmcnt + R17-style
// both-sides swizzle. LDS rows are 64B (BK=32): physical chunk
// p = g ^ ((row>>1)&3) -> 2-way residual (free, m136); glds16 source
// pre-swizzled with (tid&3)^((tid>>3)&3) (write side matches read side).
// EPI 0: fused QKV epilogue; EPI 2: fp32 acc+bias+resid; EPI 3: bf16 relu.
template<int EPI, int BN>
__global__ __launch_bounds__(256, 4) void gemm_lg(const bf16_t* __restrict__ A,
                                                  const bf16_t* __restrict__ Bt,
                                                  const float* __restrict__ bias,
                                                  const float* __restrict__ bias2,
                                                  const float* __restrict__ bias3,
                                                  const float* __restrict__ resid,
                                                  void* __restrict__ outp,
                                                  int M, int N, int K){
  constexpr int NF = BN / 32;                      // n-fragments per wave
  __shared__ bf16_t As[2][128][32];
  __shared__ bf16_t Bs[2][BN][32];
  const int tid = threadIdx.x, lane = tid & 63, wid = tid >> 6;
  const int wm = wid >> 1, wn = wid & 1;           // 2x2 waves
  const int fr = lane & 15, g = lane >> 4;
  const int m0 = blockIdx.x * 128, n0 = blockIdx.y * BN;
  const int srow  = tid >> 2;                      // 0..63 per 4KB chunk
  const int schunk = (tid & 3) ^ ((tid >> 3) & 3); // pre-swizzled source chunk
  f32x4 acc[4][NF];
  #pragma unroll
  for (int m = 0; m < 4; m++)
    #pragma unroll
    for (int n = 0; n < NF; n++) acc[m][n] = (f32x4){0, 0, 0, 0};

  const bf16_t* Ag = A  + (size_t)(m0 + srow) * K + schunk * 8;
  const bf16_t* Bg = Bt + (size_t)(n0 + srow) * K + schunk * 8;
  const int nk = K >> 5;

  auto stage = [&](int t){
    const int k0 = t << 5;
    char* la = (char*)&As[t & 1][0][0] + tid * 16;
    char* lb = (char*)&Bs[t & 1][0][0] + tid * 16;
    glds16(Ag + k0,                  la);
    glds16(Ag + (size_t)64 * K + k0, la + 4096);
    glds16(Bg + k0,                  lb);
    if constexpr (BN == 128)
      glds16(Bg + (size_t)64 * K + k0, lb + 4096);
  };

  stage(0);
  for (int t = 0; t < nk; t++){
    if (t + 1 < nk){
      stage(t + 1);
      if constexpr (BN == 128) asm volatile("s_waitcnt vmcnt(4)" ::: "memory");
      else                     asm volatile("s_waitcnt vmcnt(3)" ::: "memory");
    } else {
      asm volatile("s_waitcnt vmcnt(0)" ::: "memory");
    }
    __builtin_amdgcn_sched_barrier(0);
    __builtin_amdgcn_s_barrier();
    const char* bufA = (const char*)&As[t & 1][0][0];
    const char* bufB = (const char*)&Bs[t & 1][0][0];
    bf16x8 af[4], bfv[NF];
    #pragma unroll
    for (int m = 0; m < 4; m++){
      const int ra = wm * 64 + m * 16 + fr;
      af[m] = *(const bf16x8*)(bufA + ra * 64 + ((g ^ ((ra >> 1) & 3)) << 4));
    }
    #pragma unroll
    for (int n = 0; n < NF; n++){
      const int rb = wn * (BN / 2) + n * 16 + fr;
      bfv[n] = *(const bf16x8*)(bufB + rb * 64 + ((g ^ ((rb >> 1) & 3)) << 4));
    }
    #pragma unroll
    for (int m = 0; m < 4; m++)
      #pragma unroll
      for (int n = 0; n < NF; n++)
        acc[m][n] = mfma16(af[m], bfv[n], acc[m][n]);
    __builtin_amdgcn_sched_barrier(0);
    __builtin_amdgcn_s_barrier();
  }

  #pragma unroll
  for (int m = 0; m < 4; m++){
    #pragma unroll
    for (int n = 0; n < NF; n++){
      #pragma unroll
      for (int r = 0; r < 4; r++){
        int row = m0 + wm * 64 + m * 16 + g * 4 + r;
        int col = n0 + wn * (BN / 2) + n * 16 + fr;
        if constexpr (EPI == 0){
          int seg = col >> 10, c = col & 1023;
          int h = c >> 6, dh = c & 63;
          int b = row >> 11, sidx = row & (S_ - 1);
          const float* bp = (seg == 0) ? bias : (seg == 1) ? bias2 : bias3;
          float val = acc[m][n][r] + bp[c];
          bf16_t* base = (bf16_t*)outp + (size_t)seg * M_ * D_;
          if (seg < 2)
            base[(((size_t)b * H_ + h) * S_ + sidx) * DH_ + dh] = (bf16_t)val;
          else  // V tiled: [bh][sidx>>5][dh][sidx&31]
            base[((size_t)b * H_ + h) * (S_ * DH_) + (size_t)(sidx >> 5) * (DH_ * 32)
                 + dh * 32 + (sidx & 31)] = (bf16_t)val;
        } else if constexpr (EPI == 2){
          float val = acc[m][n][r] + bias[col];
          ((float*)outp)[(size_t)row * N + col] = val + resid[(size_t)row * N + col];
        } else {
          float val = acc[m][n][r] + bias[col];
          ((bf16_t*)outp)[(size_t)row * N + col] = (bf16_t)fmaxf(val, 0.0f);
        }
      }
    }
  }
}

// ---- 64x64-tile GEMM (R18 dbuf version) — kept for W0 (N=1024, K=1024) ----
template<int EPI>
__global__ __launch_bounds__(256, 5) void gemm_sq(const bf16_t* __restrict__ A,
                                                  const bf16_t* __restrict__ Bt,
                                                  const float* __restrict__ bias,
                                                  const float* __restrict__ resid,
                                                  void* __restrict__ outp,
                                                  int M, int N, int K){
  __shared__ bf16_t As[2][64][64];
  __shared__ bf16_t Bs[2][64][64];
  const int tid = threadIdx.x, lane = tid & 63, wid = tid >> 6;
  const int wm = wid >> 1, wn = wid & 1;
  const int fr = lane & 15, g = lane >> 4;
  const int m0 = blockIdx.x * 64, n0 = blockIdx.y * 64;
  const int srow = tid >> 3;
  const int scol = ((tid & 7) ^ (srow & 7)) * 8;
  f32x4 acc[2][2];
  #pragma unroll
  for (int m = 0; m < 2; m++)
    #pragma unroll
    for (int n = 0; n < 2; n++) acc[m][n] = (f32x4){0, 0, 0, 0};

  const bf16_t* Ag = A  + (size_t)(m0 + srow) * K + scol;
  const bf16_t* Bg = Bt + (size_t)(n0 + srow) * K + scol;
  const int nk = K >> 6;

  auto stage = [&](int t){
    const int k0 = t << 6;
    char* la = (char*)&As[t & 1][0][0] + tid * 16;
    char* lb = (char*)&Bs[t & 1][0][0] + tid * 16;
    glds16(Ag + k0,                    la);
    glds16(Ag + (size_t)32 * K + k0,   la + 4096);
    glds16(Bg + k0,                    lb);
    glds16(Bg + (size_t)32 * K + k0,   lb + 4096);
  };

  stage(0);
  for (int t = 0; t < nk; t++){
    if (t + 1 < nk){
      stage(t + 1);
      asm volatile("s_waitcnt vmcnt(4)" ::: "memory");
    } else {
      asm volatile("s_waitcnt vmcnt(0)" ::: "memory");
    }
    __builtin_amdgcn_sched_barrier(0);
    __builtin_amdgcn_s_barrier();
    const char* bufA = (const char*)&As[t & 1][0][0];
    const char* bufB = (const char*)&Bs[t & 1][0][0];
    bf16x8 af[2][2], bfv[2][2];
    #pragma unroll
    for (int m = 0; m < 2; m++){
      #pragma unroll
      for (int ks = 0; ks < 2; ks++){
        const int ra = wm * 32 + m * 16 + fr;
        af[m][ks]  = *(const bf16x8*)(bufA + ra * 128 + (((g + 4 * ks) ^ (ra & 7)) << 4));
        const int rb = wn * 32 + m * 16 + fr;
        bfv[m][ks] = *(const bf16x8*)(bufB + rb * 128 + (((g + 4 * ks) ^ (rb & 7)) << 4));
      }
    }
    #pragma unroll
    for (int ks = 0; ks < 2; ks++)
      #pragma unroll
      for (int m = 0; m < 2; m++)
        #pragma unroll
        for (int n = 0; n < 2; n++)
          acc[m][n] = mfma16(af[m][ks], bfv[n][ks], acc[m][n]);
    __builtin_amdgcn_sched_barrier(0);
    __builtin_amdgcn_s_barrier();
  }

  #pragma unroll
  for (int m = 0; m < 2; m++){
    #pragma unroll
    for (int n = 0; n < 2; n++){
      #pragma unroll
      for (int r = 0; r < 4; r++){
        int row = m0 + wm * 32 + m * 16 + g * 4 + r;
        int col = n0 + wn * 32 + n * 16 + fr;
        float val = acc[m][n][r] + bias[col];
        ((float*)outp)[(size_t)row * N + col] = val + resid[(size_t)row * N + col];
      }
    }
  }
}

// ---- causal flash attention, 4-TILE FUSED kv loop (R16 state, confirmed) ----
__device__ __forceinline__ void tile_step(bf16x8 kf00, bf16x8 kf01,
                                          bf16x8 kf10, bf16x8 kf11,
                                          bf16x8 vf0, bf16x8 vf1,
                                          bf16x8 vf2, bf16x8 vf3,
                                          int kb, int l15, int g, int g8,
                                          bf16x8 qa, bf16x8 qb, int qrow,
                                          f32x4* o, float& lsum,
                                          bf16_t* __restrict__ pw){
  f32x4 s0 = (f32x4){0,0,0,0}, s1 = (f32x4){0,0,0,0};
  s0 = mfma16(kf00, qa, s0);
  s0 = mfma16(kf01, qb, s0);
  s1 = mfma16(kf10, qa, s1);
  s1 = mfma16(kf11, qb, s1);
  float e[8];
  #pragma unroll
  for (int r = 0; r < 4; r++){
    e[r]     = (kb + r      <= qrow) ? __expf(s0[r] * 0.125f) : 0.0f;
    e[4 + r] = (kb + 16 + r <= qrow) ? __expf(s1[r] * 0.125f) : 0.0f;
  }
  lsum += (e[0]+e[1]) + (e[2]+e[3]) + (e[4]+e[5]) + (e[6]+e[7]);
  bf16x4 p0, p1;
  #pragma unroll
  for (int r = 0; r < 4; r++){ p0[r] = (bf16_t)e[r]; p1[r] = (bf16_t)e[4 + r]; }
  *(bf16x4*)&pw[l15 * 40 + g * 4]      = p0;
  *(bf16x4*)&pw[l15 * 40 + 16 + g * 4] = p1;
  bf16x8 pa = *(const bf16x8*)&pw[l15 * 40 + g8];
  o[0] = mfma16(vf0, pa, o[0]);
  o[1] = mfma16(vf1, pa, o[1]);
  o[2] = mfma16(vf2, pa, o[2]);
  o[3] = mfma16(vf3, pa, o[3]);
}

__device__ __forceinline__ void attn_emit(int q0, int lane, int wid,
                                          f32x4* o, float lsum,
                                          bf16_t* __restrict__ outp,
                                          int b, int h,
                                          bf16_t* __restrict__ tw,
                                          float (*mo)[17], float* ml){
  const int l15 = lane & 15, g = lane >> 4;
  if (wid){
    #pragma unroll
    for (int t = 0; t < 4; t++)
      #pragma unroll
      for (int r = 0; r < 4; r++) mo[lane][t * 4 + r] = o[t][r];
    ml[lane] = lsum;
  }
  __syncthreads();
  if (!wid){
    float inv = 1.0f / (lsum + ml[lane]);
    #pragma unroll
    for (int t = 0; t < 4; t++){
      bf16x4 w;
      #pragma unroll
      for (int r = 0; r < 4; r++)
        w[r] = (bf16_t)((o[t][r] + mo[lane][t * 4 + r]) * inv);
      *(bf16x4*)&tw[l15 * 72 + t * 16 + g * 4] = w;
    }
    const int rr = lane >> 3, cc = (lane & 7) * 8;
    bf16x8 r0 = *(const bf16x8*)&tw[rr * 72 + cc];
    bf16x8 r1 = *(const bf16x8*)&tw[(rr + 8) * 72 + cc];
    *(bf16x8*)&outp[((size_t)b * S_ + q0 + rr) * D_ + h * 64 + cc]     = r0;
    *(bf16x8*)&outp[((size_t)b * S_ + q0 + rr + 8) * D_ + h * 64 + cc] = r1;
  }
  __syncthreads();
}

__global__ __launch_bounds__(128, 2) void attn_k(const bf16_t* __restrict__ Q,
                                                 const bf16_t* __restrict__ Kb,
                                                 const bf16_t* __restrict__ Vt,
                                                 bf16_t* __restrict__ outp){
  __shared__ bf16_t plds[2][4][16][40];   // [wave][qtile] P buffers
  __shared__ bf16_t tlds[16][72];         // epilogue transpose (wave0)
  __shared__ float  mo[64][17];           // wave1 partial O
  __shared__ float  ml[64];               // wave1 partial l
  const int lane = threadIdx.x & 63, wid = threadIdx.x >> 6;
  // bijective XCD-affinity remap: L%8 == bh%8
  const int L = blockIdx.x + (blockIdx.y << 5);    // grid (32, 32)
  const int xcd = L & 7, j = L >> 3;               // j: 0..127
  const int bh = xcd + ((j & 3) << 3);             // 4 heads per XCD
  const int xa = j >> 2;                           // 0..31
  const int b = bh >> 4, h = bh & 15;
  const bf16_t* Qp = Q  + (size_t)bh * S_ * DH_;
  const bf16_t* Kp = Kb + (size_t)bh * S_ * DH_;
  const bf16_t* Vp = Vt + (size_t)bh * S_ * DH_;   // tiled [t][dh][32]
  const int l15 = lane & 15, g = lane >> 4, g8 = g * 8;

  const int tq0 = 127 - xa, tq1 = 64 + xa, tq2 = 63 - xa, tq3 = xa;
  const int q00 = tq0 * 16, q01 = tq1 * 16, q02 = tq2 * 16, q03 = tq3 * 16;
  const int nt0 = (tq0 >> 1) + 1, nt1 = (tq1 >> 1) + 1;
  const int nt2 = (tq2 >> 1) + 1, nt3 = (tq3 >> 1) + 1;
  const int qr0 = q00 + l15, qr1 = q01 + l15, qr2 = q02 + l15, qr3 = q03 + l15;

  bf16x8 qa0 = *(const bf16x8*)&Qp[(q00 + l15) * DH_ + g8];
  bf16x8 qb0 = *(const bf16x8*)&Qp[(q00 + l15) * DH_ + 32 + g8];
  bf16x8 qa1 = *(const bf16x8*)&Qp[(q01 + l15) * DH_ + g8];
  bf16x8 qb1 = *(const bf16x8*)&Qp[(q01 + l15) * DH_ + 32 + g8];
  bf16x8 qa2 = *(const bf16x8*)&Qp[(q02 + l15) * DH_ + g8];
  bf16x8 qb2 = *(const bf16x8*)&Qp[(q02 + l15) * DH_ + 32 + g8];
  bf16x8 qa3 = *(const bf16x8*)&Qp[(q03 + l15) * DH_ + g8];
  bf16x8 qb3 = *(const bf16x8*)&Qp[(q03 + l15) * DH_ + 32 + g8];

  f32x4 o0[4], o1[4], o2[4], o3[4];
  #pragma unroll
  for (int t = 0; t < 4; t++){
    o0[t] = (f32x4){0,0,0,0}; o1[t] = (f32x4){0,0,0,0};
    o2[t] = (f32x4){0,0,0,0}; o3[t] = (f32x4){0,0,0,0};
  }
  float ls0 = 0.0f, ls1 = 0.0f, ls2 = 0.0f, ls3 = 0.0f;
  bf16_t* pw0 = &plds[wid][0][0][0];
  bf16_t* pw1 = &plds[wid][1][0][0];
  bf16_t* pw2 = &plds[wid][2][0][0];
  bf16_t* pw3 = &plds[wid][3][0][0];

  for (int t = wid; t < nt0; t += 2){
    const int kv0 = t << 5;
    bf16x8 kf00 = *(const bf16x8*)&Kp[(kv0 + l15) * DH_ + g8];
    bf16x8 kf01 = *(const bf16x8*)&Kp[(kv0 + l15) * DH_ + 32 + g8];
    bf16x8 kf10 = *(const bf16x8*)&Kp[(kv0 + 16 + l15) * DH_ + g8];
    bf16x8 kf11 = *(const bf16x8*)&Kp[(kv0 + 16 + l15) * DH_ + 32 + g8];
    const bf16_t* Vtile = Vp + (size_t)t * (DH_ * 32);
    bf16x8 vf0 = *(const bf16x8*)&Vtile[(0 * 16 + l15) * 32 + g8];
    bf16x8 vf1 = *(const bf16x8*)&Vtile[(1 * 16 + l15) * 32 + g8];
    bf16x8 vf2 = *(const bf16x8*)&Vtile[(2 * 16 + l15) * 32 + g8];
    bf16x8 vf3 = *(const bf16x8*)&Vtile[(3 * 16 + l15) * 32 + g8];
    const int kb = kv0 + g * 4;

    tile_step(kf00,kf01,kf10,kf11, vf0,vf1,vf2,vf3, kb,l15,g,g8,
              qa0,qb0,qr0, o0, ls0, pw0);
    if (t < nt1)
      tile_step(kf00,kf01,kf10,kf11, vf0,vf1,vf2,vf3, kb,l15,g,g8,
                qa1,qb1,qr1, o1, ls1, pw1);
    if (t < nt2)
      tile_step(kf00,kf01,kf10,kf11, vf0,vf1,vf2,vf3, kb,l15,g,g8,
                qa2,qb2,qr2, o2, ls2, pw2);
    if (t < nt3)
      tile_step(kf00,kf01,kf10,kf11, vf0,vf1,vf2,vf3, kb,l15,g,g8,
                qa3,qb3,qr3, o3, ls3, pw3);
  }

  ls0 += __shfl_xor(ls0, 16);  ls0 += __shfl_xor(ls0, 32);
  ls1 += __shfl_xor(ls1, 16);  ls1 += __shfl_xor(ls1, 32);
  ls2 += __shfl_xor(ls2, 16);  ls2 += __shfl_xor(ls2, 32);
  ls3 += __shfl_xor(ls3, 16);  ls3 += __shfl_xor(ls3, 32);

  attn_emit(q00, lane, wid, o0, ls0, outp, b, h, &tlds[0][0], mo, ml);
  attn_emit(q01, lane, wid, o1, ls1, outp, b, h, &tlds[0][0], mo, ml);
  attn_emit(q02, lane, wid, o2, ls2, outp, b, h, &tlds[0][0], mo, ml);
  attn_emit(q03, lane, wid, o3, ls3, outp, b, h, &tlds[0][0], mo, ml);
}

extern "C" void kernel_launch(void* const* d_in, const int* in_sizes, int n_in,
                              void* d_out, int out_size, void* d_ws, size_t ws_size,
                              hipStream_t stream){
  (void)in_sizes; (void)n_in; (void)out_size; (void)ws_size;
  const float* X  = (const float*)d_in[0];
  // d_in[1] = attention_mask (always causal tril) — handled analytically
  const float* g1 = (const float*)d_in[2];
  const float* o1 = (const float*)d_in[3];
  const float* g2 = (const float*)d_in[4];
  const float* o2 = (const float*)d_in[5];
  const float* Wq = (const float*)d_in[6];
  const float* bq = (const float*)d_in[7];
  const float* Wk = (const float*)d_in[8];
  const float* bk = (const float*)d_in[9];
  const float* Wv = (const float*)d_in[10];
  const float* bv = (const float*)d_in[11];
  const float* W0 = (const float*)d_in[12];
  const float* b0 = (const float*)d_in[13];
  const float* W1 = (const float*)d_in[14];
  const float* b1 = (const float*)d_in[15];
  const float* W2 = (const float*)d_in[16];
  const float* b2 = (const float*)d_in[17];

  char* ws = (char*)d_ws;
  const size_t MB = 1024 * 1024;
  bf16_t* Xn1    = (bf16_t*)(ws + 0);
  bf16_t* attn   = (bf16_t*)(ws + 0);
  bf16_t* Wqkvt  = (bf16_t*)(ws + 8  * MB);
  bf16_t* W0t    = (bf16_t*)(ws + 14 * MB);
  bf16_t* W1t    = (bf16_t*)(ws + 16 * MB);
  bf16_t* W2t    = (bf16_t*)(ws + 24 * MB);
  bf16_t* QKV    = (bf16_t*)(ws + 32 * MB);
  bf16_t* Qb     = QKV;
  bf16_t* Kbuf   = QKV + (size_t)M_ * D_;
  bf16_t* Vtb    = QKV + (size_t)2 * M_ * D_;
  bf16_t* hid    = (bf16_t*)(ws + 32 * MB);
  float*  X2     = (float*) (ws + 64 * MB);
  bf16_t* Xn2    = (bf16_t*)(ws + 80 * MB);

  dim3 b256(256), t328(32, 8);
  transpose_f2b_k<<<dim3(D_/32, DH_/32, H_), t328, 0, stream>>>(Wq, Wqkvt, D_, DH_);
  transpose_f2b_k<<<dim3(D_/32, DH_/32, H_), t328, 0, stream>>>(Wk, Wqkvt + (size_t)D_*D_, D_, DH_);
  transpose_f2b_k<<<dim3(D_/32, DH_/32, H_), t328, 0, stream>>>(Wv, Wqkvt + (size_t)2*D_*D_, D_, DH_);
  transpose_f2b_k<<<dim3(D_/32,  D_/32,  1), t328, 0, stream>>>(W0, W0t, D_,  D_);
  transpose_f2b_k<<<dim3(D_/32,  DF_/32, 1), t328, 0, stream>>>(W1, W1t, D_,  DF_);
  transpose_f2b_k<<<dim3(DF_/32, D_/32,  1), t328, 0, stream>>>(W2, W2t, DF_, D_);
  ln_k<<<dim3(M_), b256, 0, stream>>>(X, g1, o1, Xn1);
  gemm_lg<0,128><<<dim3(M_/128, 3*D_/128), b256, 0, stream>>>(Xn1, Wqkvt, bq, bk, bv, nullptr, QKV, M_, 3*D_, D_);
  attn_k<<<dim3(S_/64, B_*H_), dim3(128), 0, stream>>>(Qb, Kbuf, Vtb, attn);
  gemm_sq<2><<<dim3(M_/64, D_/64), b256, 0, stream>>>(attn, W0t, b0, X, X2, M_, D_, D_);
  ln_k<<<dim3(M_), b256, 0, stream>>>(X2, g2, o2, Xn2);
  gemm_lg<3,128><<<dim3(M_/128, DF_/128), b256, 0, stream>>>(Xn2, W1t, b1, nullptr, nullptr, nullptr, hid, M_, DF_, D_);
  gemm_lg<2,64><<<dim3(M_/128, D_/64), b256, 0, stream>>>(hid, W2t, b2, nullptr, nullptr, X2, (float*)d_out, M_, D_, DF_);
}

// Round 20
// 251.424 us; speedup vs baseline: 1.0472x; 1.0472x over previous
//
#include <hip/hip_runtime.h>

#define B_ 2
#define S_ 2048
#define D_ 1024
#define H_ 16
#define DH_ 64
#define DF_ 4096
#define M_ (B_*S_)   // 4096

typedef __bf16 bf16_t;
typedef __attribute__((ext_vector_type(4))) __bf16 bf16x4;
typedef __attribute__((ext_vector_type(8))) __bf16 bf16x8;
typedef __attribute__((ext_vector_type(4))) float f32x4;

__device__ inline f32x4 mfma16(bf16x8 a, bf16x8 b, f32x4 c){
  return __builtin_amdgcn_mfma_f32_16x16x32_bf16(a, b, c, 0, 0, 0);
}

__device__ inline void glds16(const void* g, void* l){
  __builtin_amdgcn_global_load_lds((const __attribute__((address_space(1))) void*)g,
                                   (__attribute__((address_space(3))) void*)l, 16, 0, 0);
}

// ---- batched transpose fp32 [z][K][N] -> bf16 [z][N][K] ----
__global__ __launch_bounds__(256) void transpose_f2b_k(const float* __restrict__ in,
                                                       bf16_t* __restrict__ out,
                                                       int K, int N){
  __shared__ float t[32][33];
  const size_t zoff = (size_t)blockIdx.z * K * N;
  in  += zoff; out += zoff;
  int kb = blockIdx.x * 32, nb = blockIdx.y * 32;
  for (int i = threadIdx.y; i < 32; i += 8)
    t[i][threadIdx.x] = in[(size_t)(kb + i) * N + nb + threadIdx.x];
  __syncthreads();
  for (int i = threadIdx.y; i < 32; i += 8)
    out[(size_t)(nb + i) * K + kb + threadIdx.x] = (bf16_t)t[threadIdx.x][i];
}

// ---- LayerNorm fp32 row -> bf16 ----
__global__ __launch_bounds__(256) void ln_k(const float* __restrict__ x,
                                            const float* __restrict__ g,
                                            const float* __restrict__ o,
                                            bf16_t* __restrict__ out){
  int row = blockIdx.x;
  const float* xr = x + (size_t)row * D_;
  f32x4 v = *((const f32x4*)xr + threadIdx.x);
  float s  = v[0] + v[1] + v[2] + v[3];
  float sq = v[0]*v[0] + v[1]*v[1] + v[2]*v[2] + v[3]*v[3];
  #pragma unroll
  for (int off = 1; off < 64; off <<= 1){
    s  += __shfl_xor(s, off);
    sq += __shfl_xor(sq, off);
  }
  __shared__ float ss[4], ssq[4];
  int wid = threadIdx.x >> 6;
  if ((threadIdx.x & 63) == 0){ ss[wid] = s; ssq[wid] = sq; }
  __syncthreads();
  s  = ss[0] + ss[1] + ss[2] + ss[3];
  sq = ssq[0] + ssq[1] + ssq[2] + ssq[3];
  float mean = s * (1.0f / D_);
  float var  = fmaxf(sq * (1.0f / D_) - mean * mean, 0.0f);
  float inv  = 1.0f / (sqrtf(var) + 1e-9f);
  int c = threadIdx.x * 4;
  bf16_t* orow = out + (size_t)row * D_;
  #pragma unroll
  for (int j = 0; j < 4; j++)
    orow[c + j] = (bf16_t)(g[c + j] * ((v[j] - mean) * inv) + o[c + j]);
}

// ---- 128xBN-tile GEMM, BK=32, double-buffered, counted vmcnt (R19) ----
// Used for QKV (EPI0, BN=128, 768 blocks) and W1 (EPI3, BN=128, 1024 blocks).
// W2 reverted to gemm_sq: at N=1024 the 128-wide tile leaves 2 blocks/CU
// (20% occupancy) and regressed 57->73us — blocks/CU beats traffic at these
// shapes (R19 post-mortem).
template<int EPI, int BN>
__global__ __launch_bounds__(256, 4) void gemm_lg(const bf16_t* __restrict__ A,
                                                  const bf16_t* __restrict__ Bt,
                                                  const float* __restrict__ bias,
                                                  const float* __restrict__ bias2,
                                                  const float* __restrict__ bias3,
                                                  const float* __restrict__ resid,
                                                  void* __restrict__ outp,
                                                  int M, int N, int K){
  constexpr int NF = BN / 32;                      // n-fragments per wave
  __shared__ bf16_t As[2][128][32];
  __shared__ bf16_t Bs[2][BN][32];
  const int tid = threadIdx.x, lane = tid & 63, wid = tid >> 6;
  const int wm = wid >> 1, wn = wid & 1;           // 2x2 waves
  const int fr = lane & 15, g = lane >> 4;
  const int m0 = blockIdx.x * 128, n0 = blockIdx.y * BN;
  const int srow  = tid >> 2;                      // 0..63 per 4KB chunk
  const int schunk = (tid & 3) ^ ((tid >> 3) & 3); // pre-swizzled source chunk
  f32x4 acc[4][NF];
  #pragma unroll
  for (int m = 0; m < 4; m++)
    #pragma unroll
    for (int n = 0; n < NF; n++) acc[m][n] = (f32x4){0, 0, 0, 0};

  const bf16_t* Ag = A  + (size_t)(m0 + srow) * K + schunk * 8;
  const bf16_t* Bg = Bt + (size_t)(n0 + srow) * K + schunk * 8;
  const int nk = K >> 5;

  auto stage = [&](int t){
    const int k0 = t << 5;
    char* la = (char*)&As[t & 1][0][0] + tid * 16;
    char* lb = (char*)&Bs[t & 1][0][0] + tid * 16;
    glds16(Ag + k0,                  la);
    glds16(Ag + (size_t)64 * K + k0, la + 4096);
    glds16(Bg + k0,                  lb);
    if constexpr (BN == 128)
      glds16(Bg + (size_t)64 * K + k0, lb + 4096);
  };

  stage(0);
  for (int t = 0; t < nk; t++){
    if (t + 1 < nk){
      stage(t + 1);
      if constexpr (BN == 128) asm volatile("s_waitcnt vmcnt(4)" ::: "memory");
      else                     asm volatile("s_waitcnt vmcnt(3)" ::: "memory");
    } else {
      asm volatile("s_waitcnt vmcnt(0)" ::: "memory");
    }
    __builtin_amdgcn_sched_barrier(0);
    __builtin_amdgcn_s_barrier();
    const char* bufA = (const char*)&As[t & 1][0][0];
    const char* bufB = (const char*)&Bs[t & 1][0][0];
    bf16x8 af[4], bfv[NF];
    #pragma unroll
    for (int m = 0; m < 4; m++){
      const int ra = wm * 64 + m * 16 + fr;
      af[m] = *(const bf16x8*)(bufA + ra * 64 + ((g ^ ((ra >> 1) & 3)) << 4));
    }
    #pragma unroll
    for (int n = 0; n < NF; n++){
      const int rb = wn * (BN / 2) + n * 16 + fr;
      bfv[n] = *(const bf16x8*)(bufB + rb * 64 + ((g ^ ((rb >> 1) & 3)) << 4));
    }
    #pragma unroll
    for (int m = 0; m < 4; m++)
      #pragma unroll
      for (int n = 0; n < NF; n++)
        acc[m][n] = mfma16(af[m], bfv[n], acc[m][n]);
    __builtin_amdgcn_sched_barrier(0);
    __builtin_amdgcn_s_barrier();
  }

  #pragma unroll
  for (int m = 0; m < 4; m++){
    #pragma unroll
    for (int n = 0; n < NF; n++){
      #pragma unroll
      for (int r = 0; r < 4; r++){
        int row = m0 + wm * 64 + m * 16 + g * 4 + r;
        int col = n0 + wn * (BN / 2) + n * 16 + fr;
        if constexpr (EPI == 0){
          int seg = col >> 10, c = col & 1023;
          int h = c >> 6, dh = c & 63;
          int b = row >> 11, sidx = row & (S_ - 1);
          const float* bp = (seg == 0) ? bias : (seg == 1) ? bias2 : bias3;
          float val = acc[m][n][r] + bp[c];
          bf16_t* base = (bf16_t*)outp + (size_t)seg * M_ * D_;
          if (seg < 2)
            base[(((size_t)b * H_ + h) * S_ + sidx) * DH_ + dh] = (bf16_t)val;
          else  // V tiled: [bh][sidx>>5][dh][sidx&31]
            base[((size_t)b * H_ + h) * (S_ * DH_) + (size_t)(sidx >> 5) * (DH_ * 32)
                 + dh * 32 + (sidx & 31)] = (bf16_t)val;
        } else if constexpr (EPI == 2){
          float val = acc[m][n][r] + bias[col];
          ((float*)outp)[(size_t)row * N + col] = val + resid[(size_t)row * N + col];
        } else {
          float val = acc[m][n][r] + bias[col];
          ((bf16_t*)outp)[(size_t)row * N + col] = (bf16_t)fmaxf(val, 0.0f);
        }
      }
    }
  }
}

// ---- 64x64-tile GEMM (R18 dbuf) for N=1024 shapes (W0, W2) ----
// R20: + y-affinity XCD remap (REQUIRES grid (64,16)): bn = (flat&7)*2+(j&1)
// pins each B-panel's 64 consumer blocks to ONE XCD -> each B panel fills one
// L2 instead of 8, halving L3->L2 fill traffic (candidate residual bound at
// 18.7 TB/s observed L2 rate). Bijective: flat in [0,1024) -> (bm in [0,64),
// bn in [0,16)) each hit once.
template<int EPI>
__global__ __launch_bounds__(256, 5) void gemm_sq(const bf16_t* __restrict__ A,
                                                  const bf16_t* __restrict__ Bt,
                                                  const float* __restrict__ bias,
                                                  const float* __restrict__ resid,
                                                  void* __restrict__ outp,
                                                  int M, int N, int K){
  __shared__ bf16_t As[2][64][64];
  __shared__ bf16_t Bs[2][64][64];
  const int tid = threadIdx.x, lane = tid & 63, wid = tid >> 6;
  const int wm = wid >> 1, wn = wid & 1;
  const int fr = lane & 15, g = lane >> 4;
  // y-affinity remap (grid must be (64,16))
  const int flat = blockIdx.x + (blockIdx.y << 6);
  const int xcd = flat & 7, j = flat >> 3;
  const int m0 = (j >> 1) * 64, n0 = ((xcd << 1) | (j & 1)) * 64;
  const int srow = tid >> 3;
  const int scol = ((tid & 7) ^ (srow & 7)) * 8;
  f32x4 acc[2][2];
  #pragma unroll
  for (int m = 0; m < 2; m++)
    #pragma unroll
    for (int n = 0; n < 2; n++) acc[m][n] = (f32x4){0, 0, 0, 0};

  const bf16_t* Ag = A  + (size_t)(m0 + srow) * K + scol;
  const bf16_t* Bg = Bt + (size_t)(n0 + srow) * K + scol;
  const int nk = K >> 6;

  auto stage = [&](int t){
    const int k0 = t << 6;
    char* la = (char*)&As[t & 1][0][0] + tid * 16;
    char* lb = (char*)&Bs[t & 1][0][0] + tid * 16;
    glds16(Ag + k0,                    la);
    glds16(Ag + (size_t)32 * K + k0,   la + 4096);
    glds16(Bg + k0,                    lb);
    glds16(Bg + (size_t)32 * K + k0,   lb + 4096);
  };

  stage(0);
  for (int t = 0; t < nk; t++){
    if (t + 1 < nk){
      stage(t + 1);
      asm volatile("s_waitcnt vmcnt(4)" ::: "memory");
    } else {
      asm volatile("s_waitcnt vmcnt(0)" ::: "memory");
    }
    __builtin_amdgcn_sched_barrier(0);
    __builtin_amdgcn_s_barrier();
    const char* bufA = (const char*)&As[t & 1][0][0];
    const char* bufB = (const char*)&Bs[t & 1][0][0];
    bf16x8 af[2][2], bfv[2][2];
    #pragma unroll
    for (int m = 0; m < 2; m++){
      #pragma unroll
      for (int ks = 0; ks < 2; ks++){
        const int ra = wm * 32 + m * 16 + fr;
        af[m][ks]  = *(const bf16x8*)(bufA + ra * 128 + (((g + 4 * ks) ^ (ra & 7)) << 4));
        const int rb = wn * 32 + m * 16 + fr;
        bfv[m][ks] = *(const bf16x8*)(bufB + rb * 128 + (((g + 4 * ks) ^ (rb & 7)) << 4));
      }
    }
    #pragma unroll
    for (int ks = 0; ks < 2; ks++)
      #pragma unroll
      for (int m = 0; m < 2; m++)
        #pragma unroll
        for (int n = 0; n < 2; n++)
          acc[m][n] = mfma16(af[m][ks], bfv[n][ks], acc[m][n]);
    __builtin_amdgcn_sched_barrier(0);
    __builtin_amdgcn_s_barrier();
  }

  #pragma unroll
  for (int m = 0; m < 2; m++){
    #pragma unroll
    for (int n = 0; n < 2; n++){
      #pragma unroll
      for (int r = 0; r < 4; r++){
        int row = m0 + wm * 32 + m * 16 + g * 4 + r;
        int col = n0 + wn * 32 + n * 16 + fr;
        float val = acc[m][n][r] + bias[col];
        ((float*)outp)[(size_t)row * N + col] = val + resid[(size_t)row * N + col];
      }
    }
  }
}

// ---- causal flash attention, 4-TILE FUSED kv loop (R16 state, confirmed) ----
__device__ __forceinline__ void tile_step(bf16x8 kf00, bf16x8 kf01,
                                          bf16x8 kf10, bf16x8 kf11,
                                          bf16x8 vf0, bf16x8 vf1,
                                          bf16x8 vf2, bf16x8 vf3,
                                          int kb, int l15, int g, int g8,
                                          bf16x8 qa, bf16x8 qb, int qrow,
                                          f32x4* o, float& lsum,
                                          bf16_t* __restrict__ pw){
  f32x4 s0 = (f32x4){0,0,0,0}, s1 = (f32x4){0,0,0,0};
  s0 = mfma16(kf00, qa, s0);
  s0 = mfma16(kf01, qb, s0);
  s1 = mfma16(kf10, qa, s1);
  s1 = mfma16(kf11, qb, s1);
  float e[8];
  #pragma unroll
  for (int r = 0; r < 4; r++){
    e[r]     = (kb + r      <= qrow) ? __expf(s0[r] * 0.125f) : 0.0f;
    e[4 + r] = (kb + 16 + r <= qrow) ? __expf(s1[r] * 0.125f) : 0.0f;
  }
  lsum += (e[0]+e[1]) + (e[2]+e[3]) + (e[4]+e[5]) + (e[6]+e[7]);
  bf16x4 p0, p1;
  #pragma unroll
  for (int r = 0; r < 4; r++){ p0[r] = (bf16_t)e[r]; p1[r] = (bf16_t)e[4 + r]; }
  *(bf16x4*)&pw[l15 * 40 + g * 4]      = p0;
  *(bf16x4*)&pw[l15 * 40 + 16 + g * 4] = p1;
  bf16x8 pa = *(const bf16x8*)&pw[l15 * 40 + g8];
  o[0] = mfma16(vf0, pa, o[0]);
  o[1] = mfma16(vf1, pa, o[1]);
  o[2] = mfma16(vf2, pa, o[2]);
  o[3] = mfma16(vf3, pa, o[3]);
}

__device__ __forceinline__ void attn_emit(int q0, int lane, int wid,
                                          f32x4* o, float lsum,
                                          bf16_t* __restrict__ outp,
                                          int b, int h,
                                          bf16_t* __restrict__ tw,
                                          float (*mo)[17], float* ml){
  const int l15 = lane & 15, g = lane >> 4;
  if (wid){
    #pragma unroll
    for (int t = 0; t < 4; t++)
      #pragma unroll
      for (int r = 0; r < 4; r++) mo[lane][t * 4 + r] = o[t][r];
    ml[lane] = lsum;
  }
  __syncthreads();
  if (!wid){
    float inv = 1.0f / (lsum + ml[lane]);
    #pragma unroll
    for (int t = 0; t < 4; t++){
      bf16x4 w;
      #pragma unroll
      for (int r = 0; r < 4; r++)
        w[r] = (bf16_t)((o[t][r] + mo[lane][t * 4 + r]) * inv);
      *(bf16x4*)&tw[l15 * 72 + t * 16 + g * 4] = w;
    }
    const int rr = lane >> 3, cc = (lane & 7) * 8;
    bf16x8 r0 = *(const bf16x8*)&tw[rr * 72 + cc];
    bf16x8 r1 = *(const bf16x8*)&tw[(rr + 8) * 72 + cc];
    *(bf16x8*)&outp[((size_t)b * S_ + q0 + rr) * D_ + h * 64 + cc]     = r0;
    *(bf16x8*)&outp[((size_t)b * S_ + q0 + rr + 8) * D_ + h * 64 + cc] = r1;
  }
  __syncthreads();
}

__global__ __launch_bounds__(128, 2) void attn_k(const bf16_t* __restrict__ Q,
                                                 const bf16_t* __restrict__ Kb,
                                                 const bf16_t* __restrict__ Vt,
                                                 bf16_t* __restrict__ outp){
  __shared__ bf16_t plds[2][4][16][40];   // [wave][qtile] P buffers
  __shared__ bf16_t tlds[16][72];         // epilogue transpose (wave0)
  __shared__ float  mo[64][17];           // wave1 partial O
  __shared__ float  ml[64];               // wave1 partial l
  const int lane = threadIdx.x & 63, wid = threadIdx.x >> 6;
  // bijective XCD-affinity remap: L%8 == bh%8
  const int L = blockIdx.x + (blockIdx.y << 5);    // grid (32, 32)
  const int xcd = L & 7, j = L >> 3;               // j: 0..127
  const int bh = xcd + ((j & 3) << 3);             // 4 heads per XCD
  const int xa = j >> 2;                           // 0..31
  const int b = bh >> 4, h = bh & 15;
  const bf16_t* Qp = Q  + (size_t)bh * S_ * DH_;
  const bf16_t* Kp = Kb + (size_t)bh * S_ * DH_;
  const bf16_t* Vp = Vt + (size_t)bh * S_ * DH_;   // tiled [t][dh][32]
  const int l15 = lane & 15, g = lane >> 4, g8 = g * 8;

  const int tq0 = 127 - xa, tq1 = 64 + xa, tq2 = 63 - xa, tq3 = xa;
  const int q00 = tq0 * 16, q01 = tq1 * 16, q02 = tq2 * 16, q03 = tq3 * 16;
  const int nt0 = (tq0 >> 1) + 1, nt1 = (tq1 >> 1) + 1;
  const int nt2 = (tq2 >> 1) + 1, nt3 = (tq3 >> 1) + 1;
  const int qr0 = q00 + l15, qr1 = q01 + l15, qr2 = q02 + l15, qr3 = q03 + l15;

  bf16x8 qa0 = *(const bf16x8*)&Qp[(q00 + l15) * DH_ + g8];
  bf16x8 qb0 = *(const bf16x8*)&Qp[(q00 + l15) * DH_ + 32 + g8];
  bf16x8 qa1 = *(const bf16x8*)&Qp[(q01 + l15) * DH_ + g8];
  bf16x8 qb1 = *(const bf16x8*)&Qp[(q01 + l15) * DH_ + 32 + g8];
  bf16x8 qa2 = *(const bf16x8*)&Qp[(q02 + l15) * DH_ + g8];
  bf16x8 qb2 = *(const bf16x8*)&Qp[(q02 + l15) * DH_ + 32 + g8];
  bf16x8 qa3 = *(const bf16x8*)&Qp[(q03 + l15) * DH_ + g8];
  bf16x8 qb3 = *(const bf16x8*)&Qp[(q03 + l15) * DH_ + 32 + g8];

  f32x4 o0[4], o1[4], o2[4], o3[4];
  #pragma unroll
  for (int t = 0; t < 4; t++){
    o0[t] = (f32x4){0,0,0,0}; o1[t] = (f32x4){0,0,0,0};
    o2[t] = (f32x4){0,0,0,0}; o3[t] = (f32x4){0,0,0,0};
  }
  float ls0 = 0.0f, ls1 = 0.0f, ls2 = 0.0f, ls3 = 0.0f;
  bf16_t* pw0 = &plds[wid][0][0][0];
  bf16_t* pw1 = &plds[wid][1][0][0];
  bf16_t* pw2 = &plds[wid][2][0][0];
  bf16_t* pw3 = &plds[wid][3][0][0];

  for (int t = wid; t < nt0; t += 2){
    const int kv0 = t << 5;
    bf16x8 kf00 = *(const bf16x8*)&Kp[(kv0 + l15) * DH_ + g8];
    bf16x8 kf01 = *(const bf16x8*)&Kp[(kv0 + l15) * DH_ + 32 + g8];
    bf16x8 kf10 = *(const bf16x8*)&Kp[(kv0 + 16 + l15) * DH_ + g8];
    bf16x8 kf11 = *(const bf16x8*)&Kp[(kv0 + 16 + l15) * DH_ + 32 + g8];
    const bf16_t* Vtile = Vp + (size_t)t * (DH_ * 32);
    bf16x8 vf0 = *(const bf16x8*)&Vtile[(0 * 16 + l15) * 32 + g8];
    bf16x8 vf1 = *(const bf16x8*)&Vtile[(1 * 16 + l15) * 32 + g8];
    bf16x8 vf2 = *(const bf16x8*)&Vtile[(2 * 16 + l15) * 32 + g8];
    bf16x8 vf3 = *(const bf16x8*)&Vtile[(3 * 16 + l15) * 32 + g8];
    const int kb = kv0 + g * 4;

    tile_step(kf00,kf01,kf10,kf11, vf0,vf1,vf2,vf3, kb,l15,g,g8,
              qa0,qb0,qr0, o0, ls0, pw0);
    if (t < nt1)
      tile_step(kf00,kf01,kf10,kf11, vf0,vf1,vf2,vf3, kb,l15,g,g8,
                qa1,qb1,qr1, o1, ls1, pw1);
    if (t < nt2)
      tile_step(kf00,kf01,kf10,kf11, vf0,vf1,vf2,vf3, kb,l15,g,g8,
                qa2,qb2,qr2, o2, ls2, pw2);
    if (t < nt3)
      tile_step(kf00,kf01,kf10,kf11, vf0,vf1,vf2,vf3, kb,l15,g,g8,
                qa3,qb3,qr3, o3, ls3, pw3);
  }

  ls0 += __shfl_xor(ls0, 16);  ls0 += __shfl_xor(ls0, 32);
  ls1 += __shfl_xor(ls1, 16);  ls1 += __shfl_xor(ls1, 32);
  ls2 += __shfl_xor(ls2, 16);  ls2 += __shfl_xor(ls2, 32);
  ls3 += __shfl_xor(ls3, 16);  ls3 += __shfl_xor(ls3, 32);

  attn_emit(q00, lane, wid, o0, ls0, outp, b, h, &tlds[0][0], mo, ml);
  attn_emit(q01, lane, wid, o1, ls1, outp, b, h, &tlds[0][0], mo, ml);
  attn_emit(q02, lane, wid, o2, ls2, outp, b, h, &tlds[0][0], mo, ml);
  attn_emit(q03, lane, wid, o3, ls3, outp, b, h, &tlds[0][0], mo, ml);
}

extern "C" void kernel_launch(void* const* d_in, const int* in_sizes, int n_in,
                              void* d_out, int out_size, void* d_ws, size_t ws_size,
                              hipStream_t stream){
  (void)in_sizes; (void)n_in; (void)out_size; (void)ws_size;
  const float* X  = (const float*)d_in[0];
  // d_in[1] = attention_mask (always causal tril) — handled analytically
  const float* g1 = (const float*)d_in[2];
  const float* o1 = (const float*)d_in[3];
  const float* g2 = (const float*)d_in[4];
  const float* o2 = (const float*)d_in[5];
  const float* Wq = (const float*)d_in[6];
  const float* bq = (const float*)d_in[7];
  const float* Wk = (const float*)d_in[8];
  const float* bk = (const float*)d_in[9];
  const float* Wv = (const float*)d_in[10];
  const float* bv = (const float*)d_in[11];
  const float* W0 = (const float*)d_in[12];
  const float* b0 = (const float*)d_in[13];
  const float* W1 = (const float*)d_in[14];
  const float* b1 = (const float*)d_in[15];
  const float* W2 = (const float*)d_in[16];
  const float* b2 = (const float*)d_in[17];

  char* ws = (char*)d_ws;
  const size_t MB = 1024 * 1024;
  bf16_t* Xn1    = (bf16_t*)(ws + 0);
  bf16_t* attn   = (bf16_t*)(ws + 0);
  bf16_t* Wqkvt  = (bf16_t*)(ws + 8  * MB);
  bf16_t* W0t    = (bf16_t*)(ws + 14 * MB);
  bf16_t* W1t    = (bf16_t*)(ws + 16 * MB);
  bf16_t* W2t    = (bf16_t*)(ws + 24 * MB);
  bf16_t* QKV    = (bf16_t*)(ws + 32 * MB);
  bf16_t* Qb     = QKV;
  bf16_t* Kbuf   = QKV + (size_t)M_ * D_;
  bf16_t* Vtb    = QKV + (size_t)2 * M_ * D_;
  bf16_t* hid    = (bf16_t*)(ws + 32 * MB);
  float*  X2     = (float*) (ws + 64 * MB);
  bf16_t* Xn2    = (bf16_t*)(ws + 80 * MB);

  dim3 b256(256), t328(32, 8);
  transpose_f2b_k<<<dim3(D_/32, DH_/32, H_), t328, 0, stream>>>(Wq, Wqkvt, D_, DH_);
  transpose_f2b_k<<<dim3(D_/32, DH_/32, H_), t328, 0, stream>>>(Wk, Wqkvt + (size_t)D_*D_, D_, DH_);
  transpose_f2b_k<<<dim3(D_/32, DH_/32, H_), t328, 0, stream>>>(Wv, Wqkvt + (size_t)2*D_*D_, D_, DH_);
  transpose_f2b_k<<<dim3(D_/32,  D_/32,  1), t328, 0, stream>>>(W0, W0t, D_,  D_);
  transpose_f2b_k<<<dim3(D_/32,  DF_/32, 1), t328, 0, stream>>>(W1, W1t, D_,  DF_);
  transpose_f2b_k<<<dim3(DF_/32, D_/32,  1), t328, 0, stream>>>(W2, W2t, DF_, D_);
  ln_k<<<dim3(M_), b256, 0, stream>>>(X, g1, o1, Xn1);
  gemm_lg<0,128><<<dim3(M_/128, 3*D_/128), b256, 0, stream>>>(Xn1, Wqkvt, bq, bk, bv, nullptr, QKV, M_, 3*D_, D_);
  attn_k<<<dim3(S_/64, B_*H_), dim3(128), 0, stream>>>(Qb, Kbuf, Vtb, attn);
  gemm_sq<2><<<dim3(M_/64, D_/64), b256, 0, stream>>>(attn, W0t, b0, X, X2, M_, D_, D_);
  ln_k<<<dim3(M_), b256, 0, stream>>>(X2, g2, o2, Xn2);
  gemm_lg<3,128><<<dim3(M_/128, DF_/128), b256, 0, stream>>>(Xn2, W1t, b1, nullptr, nullptr, nullptr, hid, M_, DF_, D_);
  gemm_sq<2><<<dim3(M_/64, D_/64), b256, 0, stream>>>(hid, W2t, b2, X2, (float*)d_out, M_, D_, DF_);
}

// Round 21
// 242.864 us; speedup vs baseline: 1.0841x; 1.0352x over previous
//
#include <hip/hip_runtime.h>

#define B_ 2
#define S_ 2048
#define D_ 1024
#define H_ 16
#define DH_ 64
#define DF_ 4096
#define M_ (B_*S_)   // 4096

typedef __bf16 bf16_t;
typedef __attribute__((ext_vector_type(4))) __bf16 bf16x4;
typedef __attribute__((ext_vector_type(8))) __bf16 bf16x8;
typedef __attribute__((ext_vector_type(4))) float f32x4;

__device__ inline f32x4 mfma16(bf16x8 a, bf16x8 b, f32x4 c){
  return __builtin_amdgcn_mfma_f32_16x16x32_bf16(a, b, c, 0, 0, 0);
}

__device__ inline void glds16(const void* g, void* l){
  __builtin_amdgcn_global_load_lds((const __attribute__((address_space(1))) void*)g,
                                   (__attribute__((address_space(3))) void*)l, 16, 0, 0);
}

// ---- batched transpose fp32 [z][K][N] -> bf16 [z][N][K] ----
__global__ __launch_bounds__(256) void transpose_f2b_k(const float* __restrict__ in,
                                                       bf16_t* __restrict__ out,
                                                       int K, int N){
  __shared__ float t[32][33];
  const size_t zoff = (size_t)blockIdx.z * K * N;
  in  += zoff; out += zoff;
  int kb = blockIdx.x * 32, nb = blockIdx.y * 32;
  for (int i = threadIdx.y; i < 32; i += 8)
    t[i][threadIdx.x] = in[(size_t)(kb + i) * N + nb + threadIdx.x];
  __syncthreads();
  for (int i = threadIdx.y; i < 32; i += 8)
    out[(size_t)(nb + i) * K + kb + threadIdx.x] = (bf16_t)t[threadIdx.x][i];
}

// ---- R21: fused QKV weight repack: z in [0,48) selects Wq/Wk/Wv slice ----
// [H][D][DH] fp32 -> [h*64+dh][d] bf16, three weights in one launch.
__global__ __launch_bounds__(256) void repack_qkv3_k(const float* __restrict__ wq,
                                                     const float* __restrict__ wk,
                                                     const float* __restrict__ wv,
                                                     bf16_t* __restrict__ out){
  __shared__ float t[32][33];
  const int z = blockIdx.z;                 // 0..47
  const int which = z >> 4, hz = z & 15;    // weight index, head
  const float* in = (which == 0) ? wq : (which == 1) ? wk : wv;
  in  += (size_t)hz * D_ * DH_;             // [D][DH] slice
  bf16_t* o = out + (size_t)which * D_ * D_ + (size_t)hz * DH_ * D_;  // [DH][D] dest
  int kb = blockIdx.x * 32, nb = blockIdx.y * 32;   // k over D, n over DH
  for (int i = threadIdx.y; i < 32; i += 8)
    t[i][threadIdx.x] = in[(size_t)(kb + i) * DH_ + nb + threadIdx.x];
  __syncthreads();
  for (int i = threadIdx.y; i < 32; i += 8)
    o[(size_t)(nb + i) * D_ + kb + threadIdx.x] = (bf16_t)t[threadIdx.x][i];
}

// ---- LayerNorm fp32 row -> bf16 ----
__global__ __launch_bounds__(256) void ln_k(const float* __restrict__ x,
                                            const float* __restrict__ g,
                                            const float* __restrict__ o,
                                            bf16_t* __restrict__ out){
  int row = blockIdx.x;
  const float* xr = x + (size_t)row * D_;
  f32x4 v = *((const f32x4*)xr + threadIdx.x);
  float s  = v[0] + v[1] + v[2] + v[3];
  float sq = v[0]*v[0] + v[1]*v[1] + v[2]*v[2] + v[3]*v[3];
  #pragma unroll
  for (int off = 1; off < 64; off <<= 1){
    s  += __shfl_xor(s, off);
    sq += __shfl_xor(sq, off);
  }
  __shared__ float ss[4], ssq[4];
  int wid = threadIdx.x >> 6;
  if ((threadIdx.x & 63) == 0){ ss[wid] = s; ssq[wid] = sq; }
  __syncthreads();
  s  = ss[0] + ss[1] + ss[2] + ss[3];
  sq = ssq[0] + ssq[1] + ssq[2] + ssq[3];
  float mean = s * (1.0f / D_);
  float var  = fmaxf(sq * (1.0f / D_) - mean * mean, 0.0f);
  float inv  = 1.0f / (sqrtf(var) + 1e-9f);
  int c = threadIdx.x * 4;
  bf16_t* orow = out + (size_t)row * D_;
  #pragma unroll
  for (int j = 0; j < 4; j++)
    orow[c + j] = (bf16_t)(g[c + j] * ((v[j] - mean) * inv) + o[c + j]);
}

// ---- 128xBN-tile GEMM, BK=32, double-buffered, counted vmcnt (R19) ----
// QKV (EPI0, BN=128) and W1 (EPI3, BN=128). W2/W0 stay on gemm_sq (R19:
// at N=1024 the 128-wide tile leaves 2 blocks/CU and regressed 57->73us).
template<int EPI, int BN>
__global__ __launch_bounds__(256, 4) void gemm_lg(const bf16_t* __restrict__ A,
                                                  const bf16_t* __restrict__ Bt,
                                                  const float* __restrict__ bias,
                                                  const float* __restrict__ bias2,
                                                  const float* __restrict__ bias3,
                                                  const float* __restrict__ resid,
                                                  void* __restrict__ outp,
                                                  int M, int N, int K){
  constexpr int NF = BN / 32;
  __shared__ bf16_t As[2][128][32];
  __shared__ bf16_t Bs[2][BN][32];
  const int tid = threadIdx.x, lane = tid & 63, wid = tid >> 6;
  const int wm = wid >> 1, wn = wid & 1;
  const int fr = lane & 15, g = lane >> 4;
  const int m0 = blockIdx.x * 128, n0 = blockIdx.y * BN;
  const int srow  = tid >> 2;
  const int schunk = (tid & 3) ^ ((tid >> 3) & 3);
  f32x4 acc[4][NF];
  #pragma unroll
  for (int m = 0; m < 4; m++)
    #pragma unroll
    for (int n = 0; n < NF; n++) acc[m][n] = (f32x4){0, 0, 0, 0};

  const bf16_t* Ag = A  + (size_t)(m0 + srow) * K + schunk * 8;
  const bf16_t* Bg = Bt + (size_t)(n0 + srow) * K + schunk * 8;
  const int nk = K >> 5;

  auto stage = [&](int t){
    const int k0 = t << 5;
    char* la = (char*)&As[t & 1][0][0] + tid * 16;
    char* lb = (char*)&Bs[t & 1][0][0] + tid * 16;
    glds16(Ag + k0,                  la);
    glds16(Ag + (size_t)64 * K + k0, la + 4096);
    glds16(Bg + k0,                  lb);
    if constexpr (BN == 128)
      glds16(Bg + (size_t)64 * K + k0, lb + 4096);
  };

  stage(0);
  for (int t = 0; t < nk; t++){
    if (t + 1 < nk){
      stage(t + 1);
      if constexpr (BN == 128) asm volatile("s_waitcnt vmcnt(4)" ::: "memory");
      else                     asm volatile("s_waitcnt vmcnt(3)" ::: "memory");
    } else {
      asm volatile("s_waitcnt vmcnt(0)" ::: "memory");
    }
    __builtin_amdgcn_sched_barrier(0);
    __builtin_amdgcn_s_barrier();
    const char* bufA = (const char*)&As[t & 1][0][0];
    const char* bufB = (const char*)&Bs[t & 1][0][0];
    bf16x8 af[4], bfv[NF];
    #pragma unroll
    for (int m = 0; m < 4; m++){
      const int ra = wm * 64 + m * 16 + fr;
      af[m] = *(const bf16x8*)(bufA + ra * 64 + ((g ^ ((ra >> 1) & 3)) << 4));
    }
    #pragma unroll
    for (int n = 0; n < NF; n++){
      const int rb = wn * (BN / 2) + n * 16 + fr;
      bfv[n] = *(const bf16x8*)(bufB + rb * 64 + ((g ^ ((rb >> 1) & 3)) << 4));
    }
    #pragma unroll
    for (int m = 0; m < 4; m++)
      #pragma unroll
      for (int n = 0; n < NF; n++)
        acc[m][n] = mfma16(af[m], bfv[n], acc[m][n]);
    __builtin_amdgcn_sched_barrier(0);
    __builtin_amdgcn_s_barrier();
  }

  #pragma unroll
  for (int m = 0; m < 4; m++){
    #pragma unroll
    for (int n = 0; n < NF; n++){
      #pragma unroll
      for (int r = 0; r < 4; r++){
        int row = m0 + wm * 64 + m * 16 + g * 4 + r;
        int col = n0 + wn * (BN / 2) + n * 16 + fr;
        if constexpr (EPI == 0){
          int seg = col >> 10, c = col & 1023;
          int h = c >> 6, dh = c & 63;
          int b = row >> 11, sidx = row & (S_ - 1);
          const float* bp = (seg == 0) ? bias : (seg == 1) ? bias2 : bias3;
          float val = acc[m][n][r] + bp[c];
          bf16_t* base = (bf16_t*)outp + (size_t)seg * M_ * D_;
          if (seg < 2)
            base[(((size_t)b * H_ + h) * S_ + sidx) * DH_ + dh] = (bf16_t)val;
          else  // V tiled: [bh][sidx>>5][dh][sidx&31]
            base[((size_t)b * H_ + h) * (S_ * DH_) + (size_t)(sidx >> 5) * (DH_ * 32)
                 + dh * 32 + (sidx & 31)] = (bf16_t)val;
        } else if constexpr (EPI == 2){
          float val = acc[m][n][r] + bias[col];
          ((float*)outp)[(size_t)row * N + col] = val + resid[(size_t)row * N + col];
        } else {
          float val = acc[m][n][r] + bias[col];
          ((bf16_t*)outp)[(size_t)row * N + col] = (bf16_t)fmaxf(val, 0.0f);
        }
      }
    }
  }
}

// ---- 64x64-tile GEMM (R18 dbuf) for N=1024 shapes (W0, W2) ----
// R21: y-affinity XCD remap REVERTED — it tripled HBM FETCH (57->143MB) by
// breaking temporal A-panel locality and cost ~3us (R20 post-mortem). The
// default m-major order already has the right reuse pattern.
template<int EPI>
__global__ __launch_bounds__(256, 5) void gemm_sq(const bf16_t* __restrict__ A,
                                                  const bf16_t* __restrict__ Bt,
                                                  const float* __restrict__ bias,
                                                  const float* __restrict__ resid,
                                                  void* __restrict__ outp,
                                                  int M, int N, int K){
  __shared__ bf16_t As[2][64][64];
  __shared__ bf16_t Bs[2][64][64];
  const int tid = threadIdx.x, lane = tid & 63, wid = tid >> 6;
  const int wm = wid >> 1, wn = wid & 1;
  const int fr = lane & 15, g = lane >> 4;
  const int m0 = blockIdx.x * 64, n0 = blockIdx.y * 64;
  const int srow = tid >> 3;
  const int scol = ((tid & 7) ^ (srow & 7)) * 8;
  f32x4 acc[2][2];
  #pragma unroll
  for (int m = 0; m < 2; m++)
    #pragma unroll
    for (int n = 0; n < 2; n++) acc[m][n] = (f32x4){0, 0, 0, 0};

  const bf16_t* Ag = A  + (size_t)(m0 + srow) * K + scol;
  const bf16_t* Bg = Bt + (size_t)(n0 + srow) * K + scol;
  const int nk = K >> 6;

  auto stage = [&](int t){
    const int k0 = t << 6;
    char* la = (char*)&As[t & 1][0][0] + tid * 16;
    char* lb = (char*)&Bs[t & 1][0][0] + tid * 16;
    glds16(Ag + k0,                    la);
    glds16(Ag + (size_t)32 * K + k0,   la + 4096);
    glds16(Bg + k0,                    lb);
    glds16(Bg + (size_t)32 * K + k0,   lb + 4096);
  };

  stage(0);
  for (int t = 0; t < nk; t++){
    if (t + 1 < nk){
      stage(t + 1);
      asm volatile("s_waitcnt vmcnt(4)" ::: "memory");
    } else {
      asm volatile("s_waitcnt vmcnt(0)" ::: "memory");
    }
    __builtin_amdgcn_sched_barrier(0);
    __builtin_amdgcn_s_barrier();
    const char* bufA = (const char*)&As[t & 1][0][0];
    const char* bufB = (const char*)&Bs[t & 1][0][0];
    bf16x8 af[2][2], bfv[2][2];
    #pragma unroll
    for (int m = 0; m < 2; m++){
      #pragma unroll
      for (int ks = 0; ks < 2; ks++){
        const int ra = wm * 32 + m * 16 + fr;
        af[m][ks]  = *(const bf16x8*)(bufA + ra * 128 + (((g + 4 * ks) ^ (ra & 7)) << 4));
        const int rb = wn * 32 + m * 16 + fr;
        bfv[m][ks] = *(const bf16x8*)(bufB + rb * 128 + (((g + 4 * ks) ^ (rb & 7)) << 4));
      }
    }
    #pragma unroll
    for (int ks = 0; ks < 2; ks++)
      #pragma unroll
      for (int m = 0; m < 2; m++)
        #pragma unroll
        for (int n = 0; n < 2; n++)
          acc[m][n] = mfma16(af[m][ks], bfv[n][ks], acc[m][n]);
    __builtin_amdgcn_sched_barrier(0);
    __builtin_amdgcn_s_barrier();
  }

  #pragma unroll
  for (int m = 0; m < 2; m++){
    #pragma unroll
    for (int n = 0; n < 2; n++){
      #pragma unroll
      for (int r = 0; r < 4; r++){
        int row = m0 + wm * 32 + m * 16 + g * 4 + r;
        int col = n0 + wn * 32 + n * 16 + fr;
        float val = acc[m][n][r] + bias[col];
        ((float*)outp)[(size_t)row * N + col] = val + resid[(size_t)row * N + col];
      }
    }
  }
}

// ---- causal flash attention, 4-TILE FUSED kv loop (R16 state, confirmed) ----
__device__ __forceinline__ void tile_step(bf16x8 kf00, bf16x8 kf01,
                                          bf16x8 kf10, bf16x8 kf11,
                                          bf16x8 vf0, bf16x8 vf1,
                                          bf16x8 vf2, bf16x8 vf3,
                                          int kb, int l15, int g, int g8,
                                          bf16x8 qa, bf16x8 qb, int qrow,
                                          f32x4* o, float& lsum,
                                          bf16_t* __restrict__ pw){
  f32x4 s0 = (f32x4){0,0,0,0}, s1 = (f32x4){0,0,0,0};
  s0 = mfma16(kf00, qa, s0);
  s0 = mfma16(kf01, qb, s0);
  s1 = mfma16(kf10, qa, s1);
  s1 = mfma16(kf11, qb, s1);
  float e[8];
  #pragma unroll
  for (int r = 0; r < 4; r++){
    e[r]     = (kb + r      <= qrow) ? __expf(s0[r] * 0.125f) : 0.0f;
    e[4 + r] = (kb + 16 + r <= qrow) ? __expf(s1[r] * 0.125f) : 0.0f;
  }
  lsum += (e[0]+e[1]) + (e[2]+e[3]) + (e[4]+e[5]) + (e[6]+e[7]);
  bf16x4 p0, p1;
  #pragma unroll
  for (int r = 0; r < 4; r++){ p0[r] = (bf16_t)e[r]; p1[r] = (bf16_t)e[4 + r]; }
  *(bf16x4*)&pw[l15 * 40 + g * 4]      = p0;
  *(bf16x4*)&pw[l15 * 40 + 16 + g * 4] = p1;
  bf16x8 pa = *(const bf16x8*)&pw[l15 * 40 + g8];
  o[0] = mfma16(vf0, pa, o[0]);
  o[1] = mfma16(vf1, pa, o[1]);
  o[2] = mfma16(vf2, pa, o[2]);
  o[3] = mfma16(vf3, pa, o[3]);
}

__device__ __forceinline__ void attn_emit(int q0, int lane, int wid,
                                          f32x4* o, float lsum,
                                          bf16_t* __restrict__ outp,
                                          int b, int h,
                                          bf16_t* __restrict__ tw,
                                          float (*mo)[17], float* ml){
  const int l15 = lane & 15, g = lane >> 4;
  if (wid){
    #pragma unroll
    for (int t = 0; t < 4; t++)
      #pragma unroll
      for (int r = 0; r < 4; r++) mo[lane][t * 4 + r] = o[t][r];
    ml[lane] = lsum;
  }
  __syncthreads();
  if (!wid){
    float inv = 1.0f / (lsum + ml[lane]);
    #pragma unroll
    for (int t = 0; t < 4; t++){
      bf16x4 w;
      #pragma unroll
      for (int r = 0; r < 4; r++)
        w[r] = (bf16_t)((o[t][r] + mo[lane][t * 4 + r]) * inv);
      *(bf16x4*)&tw[l15 * 72 + t * 16 + g * 4] = w;
    }
    const int rr = lane >> 3, cc = (lane & 7) * 8;
    bf16x8 r0 = *(const bf16x8*)&tw[rr * 72 + cc];
    bf16x8 r1 = *(const bf16x8*)&tw[(rr + 8) * 72 + cc];
    *(bf16x8*)&outp[((size_t)b * S_ + q0 + rr) * D_ + h * 64 + cc]     = r0;
    *(bf16x8*)&outp[((size_t)b * S_ + q0 + rr + 8) * D_ + h * 64 + cc] = r1;
  }
  __syncthreads();
}

__global__ __launch_bounds__(128, 2) void attn_k(const bf16_t* __restrict__ Q,
                                                 const bf16_t* __restrict__ Kb,
                                                 const bf16_t* __restrict__ Vt,
                                                 bf16_t* __restrict__ outp){
  __shared__ bf16_t plds[2][4][16][40];
  __shared__ bf16_t tlds[16][72];
  __shared__ float  mo[64][17];
  __shared__ float  ml[64];
  const int lane = threadIdx.x & 63, wid = threadIdx.x >> 6;
  const int L = blockIdx.x + (blockIdx.y << 5);    // grid (32, 32)
  const int xcd = L & 7, j = L >> 3;
  const int bh = xcd + ((j & 3) << 3);
  const int xa = j >> 2;                           // 0..31
  const int b = bh >> 4, h = bh & 15;
  const bf16_t* Qp = Q  + (size_t)bh * S_ * DH_;
  const bf16_t* Kp = Kb + (size_t)bh * S_ * DH_;
  const bf16_t* Vp = Vt + (size_t)bh * S_ * DH_;   // tiled [t][dh][32]
  const int l15 = lane & 15, g = lane >> 4, g8 = g * 8;

  const int tq0 = 127 - xa, tq1 = 64 + xa, tq2 = 63 - xa, tq3 = xa;
  const int q00 = tq0 * 16, q01 = tq1 * 16, q02 = tq2 * 16, q03 = tq3 * 16;
  const int nt0 = (tq0 >> 1) + 1, nt1 = (tq1 >> 1) + 1;
  const int nt2 = (tq2 >> 1) + 1, nt3 = (tq3 >> 1) + 1;
  const int qr0 = q00 + l15, qr1 = q01 + l15, qr2 = q02 + l15, qr3 = q03 + l15;

  bf16x8 qa0 = *(const bf16x8*)&Qp[(q00 + l15) * DH_ + g8];
  bf16x8 qb0 = *(const bf16x8*)&Qp[(q00 + l15) * DH_ + 32 + g8];
  bf16x8 qa1 = *(const bf16x8*)&Qp[(q01 + l15) * DH_ + g8];
  bf16x8 qb1 = *(const bf16x8*)&Qp[(q01 + l15) * DH_ + 32 + g8];
  bf16x8 qa2 = *(const bf16x8*)&Qp[(q02 + l15) * DH_ + g8];
  bf16x8 qb2 = *(const bf16x8*)&Qp[(q02 + l15) * DH_ + 32 + g8];
  bf16x8 qa3 = *(const bf16x8*)&Qp[(q03 + l15) * DH_ + g8];
  bf16x8 qb3 = *(const bf16x8*)&Qp[(q03 + l15) * DH_ + 32 + g8];

  f32x4 o0[4], o1[4], o2[4], o3[4];
  #pragma unroll
  for (int t = 0; t < 4; t++){
    o0[t] = (f32x4){0,0,0,0}; o1[t] = (f32x4){0,0,0,0};
    o2[t] = (f32x4){0,0,0,0}; o3[t] = (f32x4){0,0,0,0};
  }
  float ls0 = 0.0f, ls1 = 0.0f, ls2 = 0.0f, ls3 = 0.0f;
  bf16_t* pw0 = &plds[wid][0][0][0];
  bf16_t* pw1 = &plds[wid][1][0][0];
  bf16_t* pw2 = &plds[wid][2][0][0];
  bf16_t* pw3 = &plds[wid][3][0][0];

  for (int t = wid; t < nt0; t += 2){
    const int kv0 = t << 5;
    bf16x8 kf00 = *(const bf16x8*)&Kp[(kv0 + l15) * DH_ + g8];
    bf16x8 kf01 = *(const bf16x8*)&Kp[(kv0 + l15) * DH_ + 32 + g8];
    bf16x8 kf10 = *(const bf16x8*)&Kp[(kv0 + 16 + l15) * DH_ + g8];
    bf16x8 kf11 = *(const bf16x8*)&Kp[(kv0 + 16 + l15) * DH_ + 32 + g8];
    const bf16_t* Vtile = Vp + (size_t)t * (DH_ * 32);
    bf16x8 vf0 = *(const bf16x8*)&Vtile[(0 * 16 + l15) * 32 + g8];
    bf16x8 vf1 = *(const bf16x8*)&Vtile[(1 * 16 + l15) * 32 + g8];
    bf16x8 vf2 = *(const bf16x8*)&Vtile[(2 * 16 + l15) * 32 + g8];
    bf16x8 vf3 = *(const bf16x8*)&Vtile[(3 * 16 + l15) * 32 + g8];
    const int kb = kv0 + g * 4;

    tile_step(kf00,kf01,kf10,kf11, vf0,vf1,vf2,vf3, kb,l15,g,g8,
              qa0,qb0,qr0, o0, ls0, pw0);
    if (t < nt1)
      tile_step(kf00,kf01,kf10,kf11, vf0,vf1,vf2,vf3, kb,l15,g,g8,
                qa1,qb1,qr1, o1, ls1, pw1);
    if (t < nt2)
      tile_step(kf00,kf01,kf10,kf11, vf0,vf1,vf2,vf3, kb,l15,g,g8,
                qa2,qb2,qr2, o2, ls2, pw2);
    if (t < nt3)
      tile_step(kf00,kf01,kf10,kf11, vf0,vf1,vf2,vf3, kb,l15,g,g8,
                qa3,qb3,qr3, o3, ls3, pw3);
  }

  ls0 += __shfl_xor(ls0, 16);  ls0 += __shfl_xor(ls0, 32);
  ls1 += __shfl_xor(ls1, 16);  ls1 += __shfl_xor(ls1, 32);
  ls2 += __shfl_xor(ls2, 16);  ls2 += __shfl_xor(ls2, 32);
  ls3 += __shfl_xor(ls3, 16);  ls3 += __shfl_xor(ls3, 32);

  attn_emit(q00, lane, wid, o0, ls0, outp, b, h, &tlds[0][0], mo, ml);
  attn_emit(q01, lane, wid, o1, ls1, outp, b, h, &tlds[0][0], mo, ml);
  attn_emit(q02, lane, wid, o2, ls2, outp, b, h, &tlds[0][0], mo, ml);
  attn_emit(q03, lane, wid, o3, ls3, outp, b, h, &tlds[0][0], mo, ml);
}

extern "C" void kernel_launch(void* const* d_in, const int* in_sizes, int n_in,
                              void* d_out, int out_size, void* d_ws, size_t ws_size,
                              hipStream_t stream){
  (void)in_sizes; (void)n_in; (void)out_size; (void)ws_size;
  const float* X  = (const float*)d_in[0];
  // d_in[1] = attention_mask (always causal tril) — handled analytically
  const float* g1 = (const float*)d_in[2];
  const float* o1 = (const float*)d_in[3];
  const float* g2 = (const float*)d_in[4];
  const float* o2 = (const float*)d_in[5];
  const float* Wq = (const float*)d_in[6];
  const float* bq = (const float*)d_in[7];
  const float* Wk = (const float*)d_in[8];
  const float* bk = (const float*)d_in[9];
  const float* Wv = (const float*)d_in[10];
  const float* bv = (const float*)d_in[11];
  const float* W0 = (const float*)d_in[12];
  const float* b0 = (const float*)d_in[13];
  const float* W1 = (const float*)d_in[14];
  const float* b1 = (const float*)d_in[15];
  const float* W2 = (const float*)d_in[16];
  const float* b2 = (const float*)d_in[17];

  char* ws = (char*)d_ws;
  const size_t MB = 1024 * 1024;
  bf16_t* Xn1    = (bf16_t*)(ws + 0);
  bf16_t* attn   = (bf16_t*)(ws + 0);
  bf16_t* Wqkvt  = (bf16_t*)(ws + 8  * MB);
  bf16_t* W0t    = (bf16_t*)(ws + 14 * MB);
  bf16_t* W1t    = (bf16_t*)(ws + 16 * MB);
  bf16_t* W2t    = (bf16_t*)(ws + 24 * MB);
  bf16_t* QKV    = (bf16_t*)(ws + 32 * MB);
  bf16_t* Qb     = QKV;
  bf16_t* Kbuf   = QKV + (size_t)M_ * D_;
  bf16_t* Vtb    = QKV + (size_t)2 * M_ * D_;
  bf16_t* hid    = (bf16_t*)(ws + 32 * MB);
  float*  X2     = (float*) (ws + 64 * MB);
  bf16_t* Xn2    = (bf16_t*)(ws + 80 * MB);

  dim3 b256(256), t328(32, 8);
  repack_qkv3_k<<<dim3(D_/32, DH_/32, 48), t328, 0, stream>>>(Wq, Wk, Wv, Wqkvt);
  transpose_f2b_k<<<dim3(D_/32,  D_/32,  1), t328, 0, stream>>>(W0, W0t, D_,  D_);
  transpose_f2b_k<<<dim3(D_/32,  DF_/32, 1), t328, 0, stream>>>(W1, W1t, D_,  DF_);
  transpose_f2b_k<<<dim3(DF_/32, D_/32,  1), t328, 0, stream>>>(W2, W2t, DF_, D_);
  ln_k<<<dim3(M_), b256, 0, stream>>>(X, g1, o1, Xn1);
  gemm_lg<0,128><<<dim3(M_/128, 3*D_/128), b256, 0, stream>>>(Xn1, Wqkvt, bq, bk, bv, nullptr, QKV, M_, 3*D_, D_);
  attn_k<<<dim3(S_/64, B_*H_), dim3(128), 0, stream>>>(Qb, Kbuf, Vtb, attn);
  gemm_sq<2><<<dim3(M_/64, D_/64), b256, 0, stream>>>(attn, W0t, b0, X, X2, M_, D_, D_);
  ln_k<<<dim3(M_), b256, 0, stream>>>(X2, g2, o2, Xn2);
  gemm_lg<3,128><<<dim3(M_/128, DF_/128), b256, 0, stream>>>(Xn2, W1t, b1, nullptr, nullptr, nullptr, hid, M_, DF_, D_);
  gemm_sq<2><<<dim3(M_/64, D_/64), b256, 0, stream>>>(hid, W2t, b2, X2, (float*)d_out, M_, D_, DF_);
}